// Round 3
// baseline (253.952 us; speedup 1.0000x reference)
//
#include <hip/hip_runtime.h>
#include <hip/hip_bf16.h>

// ---------------- problem constants ----------------
constexpr int E_ = 16, K_ = 2, D_ = 1024, F_ = 512, T_ = 4096;
constexpr int TK_ = T_ * K_;          // 8192 (token,expert) slots
constexpr int CAP_ = 2048;            // per-expert capacity
constexpr int BM_ = 128;              // row-region alignment (offsets)
constexpr int ROWS_MAX = 10240;       // TK + E*(BM-1) rounded up

// ---------------- workspace layout (bytes) ----------------
// WdT first (live through gemm2); WgT/WuT/Xg are dead after gemm1, so the f32
// Ye buffer (42 MB) aliases them (starts at OFF_WGT, ends < OFF_H).
constexpr size_t SZ_W   = (size_t)E_ * F_ * D_ * 2;      // one bf16 weight matrix
constexpr size_t OFF_WDT  = 0;
constexpr size_t OFF_WGT  = OFF_WDT + SZ_W;
constexpr size_t OFF_WUT  = OFF_WGT + SZ_W;
constexpr size_t OFF_XG   = OFF_WUT + SZ_W;
constexpr size_t SZ_XG  = (size_t)ROWS_MAX * D_ * 2;
constexpr size_t OFF_H    = OFF_XG + SZ_XG;
constexpr size_t SZ_H   = (size_t)ROWS_MAX * F_ * 2;
constexpr size_t OFF_META = OFF_H + SZ_H;
constexpr size_t OFF_YE   = OFF_WGT;                     // f32 [ROWS_MAX][D], 42 MB
static_assert(OFF_YE + (size_t)ROWS_MAX * D_ * 4 <= OFF_H, "Ye overlaps live buffers");
// meta: cnt_c[16], off_al[16], row_token[ROWS_MAX], row_weight[ROWS_MAX], slot_row[TK]

typedef __attribute__((ext_vector_type(8))) short short8;
typedef __attribute__((ext_vector_type(4))) float float4v;

__device__ __forceinline__ unsigned short f2bf(float f) {
  union { float f; unsigned int u; } v; v.f = f;
  unsigned int r = (v.u + 0x7fffu + ((v.u >> 16) & 1u)) >> 16;
  return (unsigned short)r;
}

__device__ __forceinline__ void load_lds16(const unsigned short* g, unsigned short* l) {
  __builtin_amdgcn_global_load_lds(
      (const __attribute__((address_space(1))) unsigned int*)g,
      (__attribute__((address_space(3))) unsigned int*)l,
      16, 0, 0);
}

// ---------------- dispatch: one block per expert, redundant histogram ----------
__launch_bounds__(256)
__global__ void dispatch_k(const int* __restrict__ idx, const float* __restrict__ tw,
                           int* __restrict__ cnt_c, int* __restrict__ off_al,
                           int* __restrict__ row_token, float* __restrict__ row_weight,
                           int* __restrict__ slot_row) {
  __shared__ int hist[E_];
  __shared__ int off_s, pad_s, cnt_s;
  int e = blockIdx.x, tid = threadIdx.x;
  if (tid < E_) hist[tid] = 0;
  if (tid == 0) cnt_s = 0;
  __syncthreads();
  for (int i = tid; i < TK_; i += 256) atomicAdd(&hist[idx[i]], 1);
  __syncthreads();
  if (tid == 0) {
    int run = 0, off = 0, myc = 0;
    for (int ee = 0; ee < E_; ++ee) {
      int c = hist[ee] > CAP_ ? CAP_ : hist[ee];
      if (ee == e) { off = run; myc = c; }
      run += (c + BM_ - 1) & ~(BM_ - 1);
    }
    off_s = off; pad_s = (myc + BM_ - 1) & ~(BM_ - 1);
    cnt_c[e] = myc; off_al[e] = off;
  }
  __syncthreads();
  int off = off_s, pad = pad_s;
  for (int r = tid; r < pad; r += 256) row_token[off + r] = -1;
  __syncthreads();
  for (int i = tid; i < TK_; i += 256) {
    if (idx[i] == e) {
      int r = atomicAdd(&cnt_s, 1);
      int row = -1;
      if (r < CAP_) {
        row = off + r;
        row_token[row] = i >> 1;              // source token
        row_weight[row] = tw[i];
      }
      slot_row[i] = row;
    }
  }
}

// ---------------- gather tokens -> bf16 grouped rows ----------------
__global__ void gather_k(const float* __restrict__ hidden, const int* __restrict__ row_token,
                         unsigned short* __restrict__ Xg) {
  int r = blockIdx.x;
  int tok = row_token[r];
  int c = threadIdx.x * 4;
  ushort4 o;
  if ((unsigned)tok < (unsigned)T_) {          // clamp: tail region is uninitialized
    float4 v = *(const float4*)(hidden + (size_t)tok * D_ + c);
    o.x = f2bf(v.x); o.y = f2bf(v.y); o.z = f2bf(v.z); o.w = f2bf(v.w);
  } else {
    o.x = 0; o.y = 0; o.z = 0; o.w = 0;
  }
  *(ushort4*)(Xg + (size_t)r * D_ + c) = o;
}

// ---------------- transpose-cast: grid-stride, software-pipelined ----------------
// 2048 blocks x 3 tiles. Per tile 64x64 f32: phase-1 regs->LDS [64][65] (2-way
// free banks), issue NEXT tile's global loads before the barrier (latency hides
// under phase-2), phase-2 column-read + cvt + short8 store (2-way free banks,
// 128B store segments).
__launch_bounds__(256)
__global__ void transpose_all_k(const float* __restrict__ wg, const float* __restrict__ wu,
                                const float* __restrict__ wd,
                                unsigned short* __restrict__ WgT, unsigned short* __restrict__ WuT,
                                unsigned short* __restrict__ WdT) {
  __shared__ float tile[64][65];
  int bid = blockIdx.x;
  int lr = threadIdx.x >> 4;          // 0..15
  int lc = (threadIdx.x & 15) * 4;    // 0..60
  int w = threadIdx.x >> 6, l = threadIdx.x & 63;

  auto src_of = [&](int g, int& r0, int& c0, int& R_) -> const float* {
    int z = g >> 7, t = g & 127;
    int kind = z >> 4, e = z & 15;
    int R = (kind == 2) ? F_ : D_;
    int C = (kind == 2) ? D_ : F_;
    int tilesX = C >> 6;
    r0 = (t / tilesX) * 64; c0 = (t % tilesX) * 64; R_ = R;
    return ((kind == 0) ? wg : (kind == 1) ? wu : wd) + (size_t)e * R * C;
  };
  auto dst_of = [&](int g) -> unsigned short* {
    int z = g >> 7;
    int kind = z >> 4, e = z & 15;
    size_t n = (size_t)((kind == 2) ? F_ : D_) * ((kind == 2) ? D_ : F_);
    return ((kind == 0) ? WgT : (kind == 1) ? WuT : WdT) + (size_t)e * n;
  };

  float4 v[4], v2[4];
  int r0, c0, R;
  const float* s = src_of(bid, r0, c0, R);
  int C = (R == F_) ? D_ : F_;
#pragma unroll
  for (int it = 0; it < 4; ++it)
    v[it] = *(const float4*)(s + (size_t)(r0 + lr + it * 16) * C + (c0 + lc));

#pragma unroll
  for (int gi = 0; gi < 3; ++gi) {
    int g = gi * 2048 + bid;
    // phase-1: regs -> LDS
#pragma unroll
    for (int it = 0; it < 4; ++it) {
      int row = lr + it * 16;
      tile[row][lc + 0] = v[it].x; tile[row][lc + 1] = v[it].y;
      tile[row][lc + 2] = v[it].z; tile[row][lc + 3] = v[it].w;
    }
    // prefetch next tile into regs (in flight across the barrier)
    int nr0 = 0, nc0 = 0, nR = 0;
    if (gi < 2) {
      const float* ns = src_of(g + 2048, nr0, nc0, nR);
      int nC = (nR == F_) ? D_ : F_;
#pragma unroll
      for (int it = 0; it < 4; ++it)
        v2[it] = *(const float4*)(ns + (size_t)(nr0 + lr + it * 16) * nC + (nc0 + lc));
    }
    __syncthreads();
    // phase-2: transpose + cvt + store
    unsigned short* d = dst_of(g);
#pragma unroll
    for (int it = 0; it < 2; ++it) {
      int c = (it * 4 + w) * 8 + (l >> 3);
      int r8 = (l & 7) * 8;
      short8 o;
#pragma unroll
      for (int j = 0; j < 8; ++j) o[j] = (short)f2bf(tile[r8 + j][c]);
      *(short8*)(d + (size_t)(c0 + c) * R + (r0 + r8)) = o;
    }
    __syncthreads();
    r0 = nr0; c0 = nc0; R = nR;
#pragma unroll
    for (int it = 0; it < 4; ++it) v[it] = v2[it];
  }
}

// Swizzled LDS staging (unchanged scheme): LDS slot sl of row holds global col8
// sl ^ (row&7); fragment reads use slot (c ^ (row&7)). Bank-conflict-free.

// ---------------- GEMM1: H = silu(Xg@Wg) * (Xg@Wu), 64x64 tile, dbuf prefetch ----
__launch_bounds__(256)
__global__ void gemm1_k(const unsigned short* __restrict__ Xg,
                        const unsigned short* __restrict__ WgT,
                        const unsigned short* __restrict__ WuT,
                        unsigned short* __restrict__ Hbuf,
                        const int* __restrict__ cnt_c, const int* __restrict__ off_al) {
  int bid = blockIdx.x;
  int swz = (bid & 7) * 512 + (bid >> 3);     // 4096 blocks, 512/XCD chunk
  int e = swz >> 8, mt = (swz >> 3) & 31, nt = swz & 7;
  int cnt = cnt_c[e];
  if (mt * 64 >= cnt) return;
  int rbase = off_al[e] + mt * 64;

  __shared__ unsigned short lA[2][64 * 64];
  __shared__ unsigned short lBg[2][64 * 64];
  __shared__ unsigned short lBu[2][64 * 64];

  int tid = threadIdx.x, wid = tid >> 6, lane = tid & 63;
  int wm = wid >> 1, wn = wid & 1;
  int quad = lane >> 4, l15 = lane & 15;
  int sw = l15 & 7;

  const unsigned short* gA = Xg + (size_t)rbase * D_;
  const unsigned short* gB0 = WgT + ((size_t)e * F_ + nt * 64) * D_;
  const unsigned short* gB1 = WuT + ((size_t)e * F_ + nt * 64) * D_;

  float4v accg[2][2], accu[2][2];
#pragma unroll
  for (int i = 0; i < 2; ++i)
#pragma unroll
    for (int j = 0; j < 2; ++j) {
      accg[i][j] = (float4v){0.f, 0.f, 0.f, 0.f};
      accu[i][j] = (float4v){0.f, 0.f, 0.f, 0.f};
    }

  auto stage = [&](int buf, int k0) {
#pragma unroll
    for (int it = 0; it < 2; ++it) {
      int fw = it * 256 + wid * 64;
      int f = fw + lane;
      int row = f >> 3, c8 = (f & 7) ^ (row & 7);
      size_t go = (size_t)row * D_ + k0 + c8 * 8;
      load_lds16(gA + go, &lA[buf][fw * 8]);
      load_lds16(gB0 + go, &lBg[buf][fw * 8]);
      load_lds16(gB1 + go, &lBu[buf][fw * 8]);
    }
  };

  stage(0, 0);
  __syncthreads();

  for (int kt = 0; kt < 16; ++kt) {
    int cur = kt & 1;
    if (kt + 1 < 16) stage(cur ^ 1, (kt + 1) * 64);
#pragma unroll
    for (int kc = 0; kc < 2; ++kc) {
      short8 af[2], bg[2], bu[2];
#pragma unroll
      for (int i = 0; i < 2; ++i) {
        int r = wm * 32 + i * 16 + l15;
        af[i] = *(const short8*)&lA[cur][r * 64 + ((kc * 4 + quad) ^ sw) * 8];
      }
#pragma unroll
      for (int j = 0; j < 2; ++j) {
        int n = wn * 32 + j * 16 + l15;
        bg[j] = *(const short8*)&lBg[cur][n * 64 + ((kc * 4 + quad) ^ sw) * 8];
        bu[j] = *(const short8*)&lBu[cur][n * 64 + ((kc * 4 + quad) ^ sw) * 8];
      }
#pragma unroll
      for (int i = 0; i < 2; ++i)
#pragma unroll
        for (int j = 0; j < 2; ++j) {
          accg[i][j] = __builtin_amdgcn_mfma_f32_16x16x32_bf16(af[i], bg[j], accg[i][j], 0, 0, 0);
          accu[i][j] = __builtin_amdgcn_mfma_f32_16x16x32_bf16(af[i], bu[j], accu[i][j], 0, 0, 0);
        }
    }
    __syncthreads();
  }

  int rem = cnt - mt * 64;
#pragma unroll
  for (int i = 0; i < 2; ++i)
#pragma unroll
    for (int j = 0; j < 2; ++j)
#pragma unroll
      for (int r = 0; r < 4; ++r) {
        int row = wm * 32 + i * 16 + quad * 4 + r;
        if (row < rem) {
          float g = accg[i][j][r], u = accu[i][j][r];
          float h = (g / (1.f + __expf(-g))) * u;
          int n = nt * 64 + wn * 32 + j * 16 + l15;
          Hbuf[(size_t)(rbase + row) * F_ + n] = f2bf(h);
        }
      }
}

// ---------------- GEMM2: Ye = H @ WdT^T, plain f32 stores (no atomics) ----------
__launch_bounds__(256)
__global__ void gemm2_k(const unsigned short* __restrict__ Hbuf,
                        const unsigned short* __restrict__ WdT,
                        float* __restrict__ Ye,
                        const int* __restrict__ cnt_c, const int* __restrict__ off_al) {
  int bid = blockIdx.x;
  int swz = (bid & 7) * 512 + (bid >> 3);
  int e = swz >> 8, mt = (swz >> 3) & 31, nt = swz & 7;
  int cnt = cnt_c[e];
  if (mt * 64 >= cnt) return;
  int rbase = off_al[e] + mt * 64;

  __shared__ unsigned short lA[2][64 * 64];
  __shared__ unsigned short lB[2][128 * 64];

  int tid = threadIdx.x, wid = tid >> 6, lane = tid & 63;
  int wm = wid >> 1, wn = wid & 1;
  int quad = lane >> 4, l15 = lane & 15;
  int sw = l15 & 7;

  const unsigned short* gA = Hbuf + (size_t)rbase * F_;
  const unsigned short* gB = WdT + ((size_t)e * D_ + nt * 128) * F_;

  float4v acc[2][4];
#pragma unroll
  for (int i = 0; i < 2; ++i)
#pragma unroll
    for (int j = 0; j < 4; ++j) acc[i][j] = (float4v){0.f, 0.f, 0.f, 0.f};

  auto stage = [&](int buf, int k0) {
#pragma unroll
    for (int it = 0; it < 2; ++it) {
      int fw = it * 256 + wid * 64;
      int f = fw + lane;
      int row = f >> 3, c8 = (f & 7) ^ (row & 7);
      load_lds16(gA + (size_t)row * F_ + k0 + c8 * 8, &lA[buf][fw * 8]);
    }
#pragma unroll
    for (int it = 0; it < 4; ++it) {
      int fw = it * 256 + wid * 64;
      int f = fw + lane;
      int row = f >> 3, c8 = (f & 7) ^ (row & 7);
      load_lds16(gB + (size_t)row * F_ + k0 + c8 * 8, &lB[buf][fw * 8]);
    }
  };

  stage(0, 0);
  __syncthreads();

  for (int kt = 0; kt < 8; ++kt) {
    int cur = kt & 1;
    if (kt + 1 < 8) stage(cur ^ 1, (kt + 1) * 64);
#pragma unroll
    for (int kc = 0; kc < 2; ++kc) {
      short8 af[2], bf[4];
#pragma unroll
      for (int i = 0; i < 2; ++i) {
        int r = wm * 32 + i * 16 + l15;
        af[i] = *(const short8*)&lA[cur][r * 64 + ((kc * 4 + quad) ^ sw) * 8];
      }
#pragma unroll
      for (int j = 0; j < 4; ++j) {
        int n = wn * 64 + j * 16 + l15;
        bf[j] = *(const short8*)&lB[cur][n * 64 + ((kc * 4 + quad) ^ sw) * 8];
      }
#pragma unroll
      for (int i = 0; i < 2; ++i)
#pragma unroll
        for (int j = 0; j < 4; ++j)
          acc[i][j] = __builtin_amdgcn_mfma_f32_16x16x32_bf16(af[i], bf[j], acc[i][j], 0, 0, 0);
    }
    __syncthreads();
  }

  int rem = cnt - mt * 64;
#pragma unroll
  for (int i = 0; i < 2; ++i)
#pragma unroll
    for (int r = 0; r < 4; ++r) {
      int row = wm * 32 + i * 16 + quad * 4 + r;
      if (row < rem) {
        float* yp = Ye + (size_t)(rbase + row) * D_ + nt * 128 + wn * 64 + l15;
#pragma unroll
        for (int j = 0; j < 4; ++j) yp[j * 16] = acc[i][j][r];
      }
    }
}

// ---------------- combine: out[t] = w0*Ye[r0] + w1*Ye[r1] --------------------
__global__ void combine_k(const float* __restrict__ Ye, const int* __restrict__ slot_row,
                          const float* __restrict__ row_weight, float* __restrict__ out) {
  int t = blockIdx.x;
  int c = threadIdx.x * 4;
  int r0 = slot_row[2 * t], r1 = slot_row[2 * t + 1];
  float4 acc = {0.f, 0.f, 0.f, 0.f};
  if (r0 >= 0) {
    float w = row_weight[r0];
    float4 y = *(const float4*)(Ye + (size_t)r0 * D_ + c);
    acc.x = w * y.x; acc.y = w * y.y; acc.z = w * y.z; acc.w = w * y.w;
  }
  if (r1 >= 0) {
    float w = row_weight[r1];
    float4 y = *(const float4*)(Ye + (size_t)r1 * D_ + c);
    acc.x += w * y.x; acc.y += w * y.y; acc.z += w * y.z; acc.w += w * y.w;
  }
  *(float4*)(out + (size_t)t * D_ + c) = acc;
}

// ---------------- launch ----------------
extern "C" void kernel_launch(void* const* d_in, const int* in_sizes, int n_in,
                              void* d_out, int out_size, void* d_ws, size_t ws_size,
                              hipStream_t stream) {
  const float* hidden  = (const float*)d_in[0];
  const int*   topkidx = (const int*)d_in[1];
  const float* topkw   = (const float*)d_in[2];
  const float* w_gate  = (const float*)d_in[3];
  const float* w_up    = (const float*)d_in[4];
  const float* w_down  = (const float*)d_in[5];
  float* out = (float*)d_out;

  char* ws = (char*)d_ws;
  unsigned short* WdT = (unsigned short*)(ws + OFF_WDT);
  unsigned short* WgT = (unsigned short*)(ws + OFF_WGT);
  unsigned short* WuT = (unsigned short*)(ws + OFF_WUT);
  unsigned short* Xg  = (unsigned short*)(ws + OFF_XG);
  unsigned short* Hb  = (unsigned short*)(ws + OFF_H);
  float* Ye           = (float*)(ws + OFF_YE);   // aliases WgT/WuT/Xg (dead after gemm1)
  int* meta           = (int*)(ws + OFF_META);
  int* cnt_c     = meta;
  int* off_al    = meta + 16;
  int* row_token = meta + 32;
  float* row_weight = (float*)(meta + 32 + ROWS_MAX);
  int* slot_row  = meta + 32 + 2 * ROWS_MAX;

  dispatch_k<<<E_, 256, 0, stream>>>(topkidx, topkw, cnt_c, off_al, row_token, row_weight,
                                     slot_row);
  transpose_all_k<<<2048, 256, 0, stream>>>(w_gate, w_up, w_down, WgT, WuT, WdT);
  gather_k<<<ROWS_MAX, 256, 0, stream>>>(hidden, row_token, Xg);

  gemm1_k<<<4096, 256, 0, stream>>>(Xg, WgT, WuT, Hb, cnt_c, off_al);
  gemm2_k<<<4096, 256, 0, stream>>>(Hb, WdT, Ye, cnt_c, off_al);
  combine_k<<<T_, 256, 0, stream>>>(Ye, slot_row, row_weight, out);
}

// Round 4
// 232.741 us; speedup vs baseline: 1.0911x; 1.0911x over previous
//
#include <hip/hip_runtime.h>
#include <hip/hip_bf16.h>

// ---------------- problem constants ----------------
constexpr int E_ = 16, K_ = 2, D_ = 1024, F_ = 512, T_ = 4096;
constexpr int TK_ = T_ * K_;          // 8192 (token,expert) slots
constexpr int CAP_ = 2048;            // per-expert capacity
constexpr int BM_ = 128;              // row-region alignment (offsets)
constexpr int ROWS_MAX = 10240;       // TK + E*(BM-1) rounded up

// ---------------- workspace layout (bytes) ----------------
// WdT first (live through gemm2); WgT/WuT/Xg are dead after gemm1, so the f32
// Ye buffer (42 MB) aliases them (starts at OFF_WGT, ends < OFF_H).
constexpr size_t SZ_W   = (size_t)E_ * F_ * D_ * 2;      // one bf16 weight matrix
constexpr size_t OFF_WDT  = 0;
constexpr size_t OFF_WGT  = OFF_WDT + SZ_W;
constexpr size_t OFF_WUT  = OFF_WGT + SZ_W;
constexpr size_t OFF_XG   = OFF_WUT + SZ_W;
constexpr size_t SZ_XG  = (size_t)ROWS_MAX * D_ * 2;
constexpr size_t OFF_H    = OFF_XG + SZ_XG;
constexpr size_t SZ_H   = (size_t)ROWS_MAX * F_ * 2;
constexpr size_t OFF_META = OFF_H + SZ_H;
constexpr size_t OFF_YE   = OFF_WGT;                     // f32 [ROWS_MAX][D], 42 MB
static_assert(OFF_YE + (size_t)ROWS_MAX * D_ * 4 <= OFF_H, "Ye overlaps live buffers");
// meta: cnt_c[16], off_al[16], row_token[ROWS_MAX], row_weight[ROWS_MAX], slot_row[TK]

typedef __attribute__((ext_vector_type(8))) short short8;
typedef __attribute__((ext_vector_type(4))) float float4v;

__device__ __forceinline__ unsigned short f2bf(float f) {
  union { float f; unsigned int u; } v; v.f = f;
  unsigned int r = (v.u + 0x7fffu + ((v.u >> 16) & 1u)) >> 16;
  return (unsigned short)r;
}

__device__ __forceinline__ void load_lds16(const unsigned short* g, unsigned short* l) {
  __builtin_amdgcn_global_load_lds(
      (const __attribute__((address_space(1))) unsigned int*)g,
      (__attribute__((address_space(3))) unsigned int*)l,
      16, 0, 0);
}

// raw barrier without the compiler's vmcnt(0) drain; memory-clobber asms pin
// all memory ops (stage intrinsics, ds_reads) on their side of the barrier.
__device__ __forceinline__ void barrier_nodrain() {
  asm volatile("" ::: "memory");
  __builtin_amdgcn_s_barrier();
  asm volatile("" ::: "memory");
}

// ---------------- dispatch: hist + offsets + rank-assign + slot map, ONE block ----
__launch_bounds__(1024)
__global__ void dispatch_k(const int* __restrict__ idx, const float* __restrict__ tw,
                           int* __restrict__ cnt_c, int* __restrict__ off_al,
                           int* __restrict__ row_token, float* __restrict__ row_weight,
                           int* __restrict__ slot_row) {
  __shared__ int hist[E_], offs[E_], ctr[E_];
  int tid = threadIdx.x;
  if (tid < E_) hist[tid] = 0;
  __syncthreads();
  for (int i = tid; i < TK_; i += 1024) atomicAdd(&hist[idx[i]], 1);
  __syncthreads();
  if (tid == 0) {
    int run = 0;
    for (int e = 0; e < E_; ++e) {
      int c = hist[e] > CAP_ ? CAP_ : hist[e];
      cnt_c[e] = c; off_al[e] = run; offs[e] = run; ctr[e] = 0;
      run += (c + BM_ - 1) & ~(BM_ - 1);
    }
  }
  __syncthreads();
  for (int r = tid; r < ROWS_MAX; r += 1024) row_token[r] = -1;
  __syncthreads();
  for (int i = tid; i < TK_; i += 1024) {
    int e = idx[i];
    int r = atomicAdd(&ctr[e], 1);
    int row = -1;
    if (r < CAP_) {
      row = offs[e] + r;
      row_token[row] = i >> 1;              // source token
      row_weight[row] = tw[i];
    }
    slot_row[i] = row;
  }
}

// ---------------- gather tokens -> bf16 grouped rows ----------------
__global__ void gather_k(const float* __restrict__ hidden, const int* __restrict__ row_token,
                         unsigned short* __restrict__ Xg) {
  int r = blockIdx.x;
  int tok = row_token[r];
  int c = threadIdx.x * 4;
  ushort4 o;
  if (tok >= 0) {
    float4 v = *(const float4*)(hidden + (size_t)tok * D_ + c);
    o.x = f2bf(v.x); o.y = f2bf(v.y); o.z = f2bf(v.z); o.w = f2bf(v.w);
  } else {
    o.x = 0; o.y = 0; o.z = 0; o.w = 0;
  }
  *(ushort4*)(Xg + (size_t)r * D_ + c) = o;
}

// ---------------- transpose-cast all three weight tensors (round-2 proven) -----
// 64x64 f32 tile per block. Phase-1: 4x float4/thread -> LDS [64][65] (2-way
// free banks). Phase-2: c=(it*4+w)*8+(l>>3), r8=(l&7)*8 -> reads tile[r8+j][c]
// (2-way free banks); 16B short8 store, 128B row segments.
__launch_bounds__(256)
__global__ void transpose_all_k(const float* __restrict__ wg, const float* __restrict__ wu,
                                const float* __restrict__ wd,
                                unsigned short* __restrict__ WgT, unsigned short* __restrict__ WuT,
                                unsigned short* __restrict__ WdT) {
  __shared__ float tile[64][65];
  int z = blockIdx.y;                 // 0..47
  int kind = z >> 4, e = z & 15;
  int R = (kind == 2) ? F_ : D_;
  int C = (kind == 2) ? D_ : F_;
  const float* s = ((kind == 0) ? wg : (kind == 1) ? wu : wd) + (size_t)e * R * C;
  unsigned short* d = ((kind == 0) ? WgT : (kind == 1) ? WuT : WdT) + (size_t)e * R * C;
  int tilesX = C >> 6;                // C/64
  int t = blockIdx.x;                 // R/64 * C/64 == 128 for both shapes
  int r0 = (t / tilesX) * 64, c0 = (t % tilesX) * 64;

  int lr = threadIdx.x >> 4;          // 0..15
  int lc = (threadIdx.x & 15) * 4;    // 0..60
#pragma unroll
  for (int it = 0; it < 4; ++it) {
    int row = lr + it * 16;
    float4 v = *(const float4*)(s + (size_t)(r0 + row) * C + (c0 + lc));
    tile[row][lc + 0] = v.x; tile[row][lc + 1] = v.y;
    tile[row][lc + 2] = v.z; tile[row][lc + 3] = v.w;
  }
  __syncthreads();

  int w = threadIdx.x >> 6, l = threadIdx.x & 63;
#pragma unroll
  for (int it = 0; it < 2; ++it) {
    int c = (it * 4 + w) * 8 + (l >> 3);
    int r8 = (l & 7) * 8;
    short8 o;
#pragma unroll
    for (int j = 0; j < 8; ++j) o[j] = (short)f2bf(tile[r8 + j][c]);
    *(short8*)(d + (size_t)(c0 + c) * R + (r0 + r8)) = o;
  }
}

// Swizzled LDS staging (unchanged scheme): LDS slot sl of row holds global col8
// sl ^ (row&7); fragment reads use slot (c ^ (row&7)). Bank-conflict-free.
//
// K-loop sync (T3+T4): per step, issue next stage's 6 global_load_lds, then
// s_waitcnt vmcnt(6) (waits ONLY the previous stage's 6; new 6 stay in flight
// across the barrier), raw s_barrier, compute, raw s_barrier (frees cur buf
// for the next iteration's stage). No vmcnt(0) drain in the main loop.

// ---------------- GEMM1: H = silu(Xg@Wg) * (Xg@Wu), 64x64 tile ----------------
__launch_bounds__(256)
__global__ void gemm1_k(const unsigned short* __restrict__ Xg,
                        const unsigned short* __restrict__ WgT,
                        const unsigned short* __restrict__ WuT,
                        unsigned short* __restrict__ Hbuf,
                        const int* __restrict__ cnt_c, const int* __restrict__ off_al) {
  int bid = blockIdx.x;
  int swz = (bid & 7) * 512 + (bid >> 3);     // 4096 blocks, 512/XCD chunk
  int e = swz >> 8, mt = (swz >> 3) & 31, nt = swz & 7;
  int cnt = cnt_c[e];
  if (mt * 64 >= cnt) return;
  int rbase = off_al[e] + mt * 64;

  __shared__ unsigned short lA[2][64 * 64];
  __shared__ unsigned short lBg[2][64 * 64];
  __shared__ unsigned short lBu[2][64 * 64];

  int tid = threadIdx.x, wid = tid >> 6, lane = tid & 63;
  int wm = wid >> 1, wn = wid & 1;
  int quad = lane >> 4, l15 = lane & 15;
  int sw = l15 & 7;

  const unsigned short* gA = Xg + (size_t)rbase * D_;
  const unsigned short* gB0 = WgT + ((size_t)e * F_ + nt * 64) * D_;
  const unsigned short* gB1 = WuT + ((size_t)e * F_ + nt * 64) * D_;

  float4v accg[2][2], accu[2][2];
#pragma unroll
  for (int i = 0; i < 2; ++i)
#pragma unroll
    for (int j = 0; j < 2; ++j) {
      accg[i][j] = (float4v){0.f, 0.f, 0.f, 0.f};
      accu[i][j] = (float4v){0.f, 0.f, 0.f, 0.f};
    }

  auto stage = [&](int buf, int k0) {         // 6 global_load_lds / thread
#pragma unroll
    for (int it = 0; it < 2; ++it) {
      int fw = it * 256 + wid * 64;
      int f = fw + lane;
      int row = f >> 3, c8 = (f & 7) ^ (row & 7);
      size_t go = (size_t)row * D_ + k0 + c8 * 8;
      load_lds16(gA + go, &lA[buf][fw * 8]);
      load_lds16(gB0 + go, &lBg[buf][fw * 8]);
      load_lds16(gB1 + go, &lBu[buf][fw * 8]);
    }
  };

  stage(0, 0);

  for (int kt = 0; kt < 16; ++kt) {
    int cur = kt & 1;
    if (kt + 1 < 16) {
      stage(cur ^ 1, (kt + 1) * 64);
      asm volatile("s_waitcnt vmcnt(6)" ::: "memory");   // prev stage complete
    } else {
      asm volatile("s_waitcnt vmcnt(0)" ::: "memory");
    }
    __builtin_amdgcn_sched_barrier(0);
    barrier_nodrain();                         // everyone's prev stage complete
#pragma unroll
    for (int kc = 0; kc < 2; ++kc) {
      short8 af[2], bg[2], bu[2];
#pragma unroll
      for (int i = 0; i < 2; ++i) {
        int r = wm * 32 + i * 16 + l15;
        af[i] = *(const short8*)&lA[cur][r * 64 + ((kc * 4 + quad) ^ sw) * 8];
      }
#pragma unroll
      for (int j = 0; j < 2; ++j) {
        int n = wn * 32 + j * 16 + l15;
        bg[j] = *(const short8*)&lBg[cur][n * 64 + ((kc * 4 + quad) ^ sw) * 8];
        bu[j] = *(const short8*)&lBu[cur][n * 64 + ((kc * 4 + quad) ^ sw) * 8];
      }
#pragma unroll
      for (int i = 0; i < 2; ++i)
#pragma unroll
        for (int j = 0; j < 2; ++j) {
          accg[i][j] = __builtin_amdgcn_mfma_f32_16x16x32_bf16(af[i], bg[j], accg[i][j], 0, 0, 0);
          accu[i][j] = __builtin_amdgcn_mfma_f32_16x16x32_bf16(af[i], bu[j], accu[i][j], 0, 0, 0);
        }
    }
    barrier_nodrain();                         // cur buf free for overwrite
  }

  int rem = cnt - mt * 64;
#pragma unroll
  for (int i = 0; i < 2; ++i)
#pragma unroll
    for (int j = 0; j < 2; ++j)
#pragma unroll
      for (int r = 0; r < 4; ++r) {
        int row = wm * 32 + i * 16 + quad * 4 + r;
        if (row < rem) {
          float g = accg[i][j][r], u = accu[i][j][r];
          float h = (g / (1.f + __expf(-g))) * u;
          int n = nt * 64 + wn * 32 + j * 16 + l15;
          Hbuf[(size_t)(rbase + row) * F_ + n] = f2bf(h);
        }
      }
}

// ---------------- GEMM2: Ye = H @ WdT^T, plain f32 stores (no atomics) ----------
__launch_bounds__(256)
__global__ void gemm2_k(const unsigned short* __restrict__ Hbuf,
                        const unsigned short* __restrict__ WdT,
                        float* __restrict__ Ye,
                        const int* __restrict__ cnt_c, const int* __restrict__ off_al) {
  int bid = blockIdx.x;
  int swz = (bid & 7) * 512 + (bid >> 3);
  int e = swz >> 8, mt = (swz >> 3) & 31, nt = swz & 7;
  int cnt = cnt_c[e];
  if (mt * 64 >= cnt) return;
  int rbase = off_al[e] + mt * 64;

  __shared__ unsigned short lA[2][64 * 64];
  __shared__ unsigned short lB[2][128 * 64];

  int tid = threadIdx.x, wid = tid >> 6, lane = tid & 63;
  int wm = wid >> 1, wn = wid & 1;
  int quad = lane >> 4, l15 = lane & 15;
  int sw = l15 & 7;

  const unsigned short* gA = Hbuf + (size_t)rbase * F_;
  const unsigned short* gB = WdT + ((size_t)e * D_ + nt * 128) * F_;

  float4v acc[2][4];
#pragma unroll
  for (int i = 0; i < 2; ++i)
#pragma unroll
    for (int j = 0; j < 4; ++j) acc[i][j] = (float4v){0.f, 0.f, 0.f, 0.f};

  auto stage = [&](int buf, int k0) {         // 6 global_load_lds / thread
#pragma unroll
    for (int it = 0; it < 2; ++it) {
      int fw = it * 256 + wid * 64;
      int f = fw + lane;
      int row = f >> 3, c8 = (f & 7) ^ (row & 7);
      load_lds16(gA + (size_t)row * F_ + k0 + c8 * 8, &lA[buf][fw * 8]);
    }
#pragma unroll
    for (int it = 0; it < 4; ++it) {
      int fw = it * 256 + wid * 64;
      int f = fw + lane;
      int row = f >> 3, c8 = (f & 7) ^ (row & 7);
      load_lds16(gB + (size_t)row * F_ + k0 + c8 * 8, &lB[buf][fw * 8]);
    }
  };

  stage(0, 0);

  for (int kt = 0; kt < 8; ++kt) {
    int cur = kt & 1;
    if (kt + 1 < 8) {
      stage(cur ^ 1, (kt + 1) * 64);
      asm volatile("s_waitcnt vmcnt(6)" ::: "memory");
    } else {
      asm volatile("s_waitcnt vmcnt(0)" ::: "memory");
    }
    __builtin_amdgcn_sched_barrier(0);
    barrier_nodrain();
#pragma unroll
    for (int kc = 0; kc < 2; ++kc) {
      short8 af[2], bf[4];
#pragma unroll
      for (int i = 0; i < 2; ++i) {
        int r = wm * 32 + i * 16 + l15;
        af[i] = *(const short8*)&lA[cur][r * 64 + ((kc * 4 + quad) ^ sw) * 8];
      }
#pragma unroll
      for (int j = 0; j < 4; ++j) {
        int n = wn * 64 + j * 16 + l15;
        bf[j] = *(const short8*)&lB[cur][n * 64 + ((kc * 4 + quad) ^ sw) * 8];
      }
#pragma unroll
      for (int i = 0; i < 2; ++i)
#pragma unroll
        for (int j = 0; j < 4; ++j)
          acc[i][j] = __builtin_amdgcn_mfma_f32_16x16x32_bf16(af[i], bf[j], acc[i][j], 0, 0, 0);
    }
    barrier_nodrain();
  }

  int rem = cnt - mt * 64;
#pragma unroll
  for (int i = 0; i < 2; ++i)
#pragma unroll
    for (int r = 0; r < 4; ++r) {
      int row = wm * 32 + i * 16 + quad * 4 + r;
      if (row < rem) {
        float* yp = Ye + (size_t)(rbase + row) * D_ + nt * 128 + wn * 64 + l15;
#pragma unroll
        for (int j = 0; j < 4; ++j) yp[j * 16] = acc[i][j][r];
      }
    }
}

// ---------------- combine: out[t] = w0*Ye[r0] + w1*Ye[r1] --------------------
__global__ void combine_k(const float* __restrict__ Ye, const int* __restrict__ slot_row,
                          const float* __restrict__ row_weight, float* __restrict__ out) {
  int t = blockIdx.x;
  int c = threadIdx.x * 4;
  int r0 = slot_row[2 * t], r1 = slot_row[2 * t + 1];
  float4 acc = {0.f, 0.f, 0.f, 0.f};
  if (r0 >= 0) {
    float w = row_weight[r0];
    float4 y = *(const float4*)(Ye + (size_t)r0 * D_ + c);
    acc.x = w * y.x; acc.y = w * y.y; acc.z = w * y.z; acc.w = w * y.w;
  }
  if (r1 >= 0) {
    float w = row_weight[r1];
    float4 y = *(const float4*)(Ye + (size_t)r1 * D_ + c);
    acc.x += w * y.x; acc.y += w * y.y; acc.z += w * y.z; acc.w += w * y.w;
  }
  *(float4*)(out + (size_t)t * D_ + c) = acc;
}

// ---------------- launch ----------------
extern "C" void kernel_launch(void* const* d_in, const int* in_sizes, int n_in,
                              void* d_out, int out_size, void* d_ws, size_t ws_size,
                              hipStream_t stream) {
  const float* hidden  = (const float*)d_in[0];
  const int*   topkidx = (const int*)d_in[1];
  const float* topkw   = (const float*)d_in[2];
  const float* w_gate  = (const float*)d_in[3];
  const float* w_up    = (const float*)d_in[4];
  const float* w_down  = (const float*)d_in[5];
  float* out = (float*)d_out;

  char* ws = (char*)d_ws;
  unsigned short* WdT = (unsigned short*)(ws + OFF_WDT);
  unsigned short* WgT = (unsigned short*)(ws + OFF_WGT);
  unsigned short* WuT = (unsigned short*)(ws + OFF_WUT);
  unsigned short* Xg  = (unsigned short*)(ws + OFF_XG);
  unsigned short* Hb  = (unsigned short*)(ws + OFF_H);
  float* Ye           = (float*)(ws + OFF_YE);   // aliases WgT/WuT/Xg (dead after gemm1)
  int* meta           = (int*)(ws + OFF_META);
  int* cnt_c     = meta;
  int* off_al    = meta + 16;
  int* row_token = meta + 32;
  float* row_weight = (float*)(meta + 32 + ROWS_MAX);
  int* slot_row  = meta + 32 + 2 * ROWS_MAX;

  dispatch_k<<<1, 1024, 0, stream>>>(topkidx, topkw, cnt_c, off_al, row_token, row_weight,
                                     slot_row);
  transpose_all_k<<<dim3(128, 48), 256, 0, stream>>>(w_gate, w_up, w_down, WgT, WuT, WdT);
  gather_k<<<ROWS_MAX, 256, 0, stream>>>(hidden, row_token, Xg);

  gemm1_k<<<4096, 256, 0, stream>>>(Xg, WgT, WuT, Hb, cnt_c, off_al);
  gemm2_k<<<4096, 256, 0, stream>>>(Hb, WdT, Ye, cnt_c, off_al);
  combine_k<<<T_, 256, 0, stream>>>(Ye, slot_row, row_weight, out);
}